// Round 4
// baseline (252.174 us; speedup 1.0000x reference)
//
#include <hip/hip_runtime.h>
#include <stdint.h>

#define Mdim 8192
#define Ndim 4096
#define Kdim 2048
#define Hdim 1024

typedef __attribute__((ext_vector_type(8))) short bf16x8;
typedef __attribute__((ext_vector_type(4))) float f32x4;

__device__ __forceinline__ unsigned short f2bf(float f) {
  union { float f; unsigned u; } v; v.f = f;
  unsigned u = v.u + 0x7fffu + ((v.u >> 16) & 1u);
  return (unsigned short)(u >> 16);
}
__device__ __forceinline__ float bf2f(unsigned short s) {
  union { unsigned u; float f; } v; v.u = ((unsigned)s) << 16;
  return v.f;
}
__device__ __forceinline__ float sigmoidf_(float x) { return 1.f / (1.f + __expf(-x)); }
__device__ __forceinline__ float tanhf_(float x) { return 1.f - 2.f / (1.f + __expf(2.f * x)); }

// ---------- pack [x | h] into bf16 A[M][K] ----------
__global__ void conv_a_kernel(const float* __restrict__ x, const float* __restrict__ h,
                              unsigned short* __restrict__ A) {
  int idx = blockIdx.x * 256 + threadIdx.x;   // one 8-elem chunk each
  int m = idx >> 8;                           // 2048/8 = 256 chunks per row
  int k = (idx & 255) * 8;
  const float* src = (k < Hdim) ? (x + (size_t)m * Hdim + k)
                                : (h + (size_t)m * Hdim + (k - Hdim));
  float4 a = ((const float4*)src)[0];
  float4 b = ((const float4*)src)[1];
  union { unsigned short s[8]; int4 v; } o;
  o.s[0] = f2bf(a.x); o.s[1] = f2bf(a.y); o.s[2] = f2bf(a.z); o.s[3] = f2bf(a.w);
  o.s[4] = f2bf(b.x); o.s[5] = f2bf(b.y); o.s[6] = f2bf(b.z); o.s[7] = f2bf(b.w);
  *(int4*)(A + (size_t)idx * 8) = o.v;
}

// ---------- transpose [W_xh ; W_hh] (K x N) into bf16 Wt[N][K] ----------
__global__ void conv_w_kernel(const float* __restrict__ Wxh, const float* __restrict__ Whh,
                              unsigned short* __restrict__ Wt) {
  __shared__ float tile[32][33];
  int k0 = blockIdx.x * 32;
  int n0 = blockIdx.y * 32;
  int tx = threadIdx.x & 31, ty = threadIdx.x >> 5;  // 32 x 8
#pragma unroll
  for (int i = 0; i < 32; i += 8) {
    int k = k0 + ty + i;
    float v = (k < Hdim) ? Wxh[(size_t)k * Ndim + n0 + tx]
                         : Whh[(size_t)(k - Hdim) * Ndim + n0 + tx];
    tile[ty + i][tx] = v;
  }
  __syncthreads();
#pragma unroll
  for (int i = 0; i < 32; i += 8) {
    int n = n0 + ty + i;
    Wt[(size_t)n * Kdim + k0 + tx] = f2bf(tile[tx][ty + i]);
  }
}

// ---------- GEMM: C[M][N] (bf16) = A[M][K] * Wt[N][K]^T ----------
// 256x256 tile, BK=64, 8 waves (2M x 4N), 8-phase schedule with counted vmcnt.
// v4: ds_reads phase-shifted one phase early so their LDS retire time hides
// under the PREVIOUS quadrant's MFMA block (was serialized: reads+QUAD in the
// same barrier pair => +1536 cyc/K-tile of exposed LDS time). Quad order
// rotated to (av0,bv0),(av1,bv0),(av0,bv1),(av1,bv1) so each read lands in a
// phase where its register set is dead -> zero extra VGPR.
#define BM 256
#define BN 256
#define BK 64
#define NT (Kdim / BK)   // 32

__global__ __launch_bounds__(512, 2)
void gemm_kernel(const unsigned short* __restrict__ A, const unsigned short* __restrict__ Bt,
                 unsigned short* __restrict__ C) {
  // [dbuf][A/B][256 rows x 64 bf16] = 128 KiB
  __shared__ unsigned short lds[2][2][BM * BK];
  const int tid = threadIdx.x;
  int bid = blockIdx.x;
  int id = (bid & 7) * 64 + (bid >> 3);      // XCD swizzle (512 % 8 == 0, bijective)
  int mT = id >> 4, nT = id & 15;            // 32 x 16 tiles
  size_t m0 = (size_t)mT * BM, n0 = (size_t)nT * BN;
  const int lane = tid & 63, w = tid >> 6;
  const int wm = w >> 2, wn = w & 3;         // 2x4 waves -> 128x64 output each
  const int r16 = lane & 15, q = lane >> 4;

  const unsigned short* gA = A + m0 * Kdim;
  const unsigned short* gB = Bt + n0 * Kdim;

  // stage one half-tile (region: 0=A rows0-127, 1=A rows128-255, 2=B0, 3=B1).
  // LDS dest is linear (wave-uniform base + lane*16); the slot swizzle
  // stored_slot = logical_slot ^ (row&7) is applied on the GLOBAL source.
  auto stage = [&](int b, int kt, int region) {
    const int mat = region >> 1, half = region & 1;
    const unsigned short* g = mat ? gB : gA;
#pragma unroll
    for (int it = 0; it < 2; ++it) {
      int c = it * 512 + tid;                // 1024 chunks of 16 B per half-tile
      int rr = c >> 3, ss = c & 7;
      __builtin_amdgcn_global_load_lds(
          (const __attribute__((address_space(1))) void*)(
              g + (size_t)(half * 128 + rr) * Kdim + kt * BK + ((ss ^ (rr & 7)) << 3)),
          (__attribute__((address_space(3))) void*)(&lds[b][mat][half * (128 * BK) + c * 8]),
          16, 0, 0);
    }
  };

  f32x4 acc[8][4] = {};
  bf16x8 av0[4][2], av1[4][2], bv0[2][2], bv1[2][2];

  auto readA = [&](int cur, int mh, bf16x8 (&av)[4][2]) {
#pragma unroll
    for (int mi = 0; mi < 4; ++mi) {
      int lr = wm * 128 + mh * 64 + mi * 16 + r16;
      const unsigned short* base = &lds[cur][0][lr * BK];
#pragma unroll
      for (int ks = 0; ks < 2; ++ks)
        av[mi][ks] = *(const bf16x8*)(base + ((((ks << 2) | q) ^ (lr & 7)) << 3));
    }
  };
  auto readB = [&](int cur, int nh, bf16x8 (&bv)[2][2]) {
#pragma unroll
    for (int ni = 0; ni < 2; ++ni) {
      int lr = wn * 64 + nh * 32 + ni * 16 + r16;
      const unsigned short* base = &lds[cur][1][lr * BK];
#pragma unroll
      for (int ks = 0; ks < 2; ++ks)
        bv[ni][ks] = *(const bf16x8*)(base + ((((ks << 2) | q) ^ (lr & 7)) << 3));
    }
  };

  // one C-quadrant over full K=64: 16 MFMA, setprio-wrapped (T5)
#define QUAD(AV, BV, MI0, NI0)                                                        \
  do {                                                                                \
    __builtin_amdgcn_s_setprio(1);                                                    \
    _Pragma("unroll") for (int mi = 0; mi < 4; ++mi)                                  \
      _Pragma("unroll") for (int ni = 0; ni < 2; ++ni)                                \
        _Pragma("unroll") for (int ks = 0; ks < 2; ++ks)                              \
          acc[(MI0) + mi][(NI0) + ni] = __builtin_amdgcn_mfma_f32_16x16x32_bf16(      \
              AV[mi][ks], BV[ni][ks], acc[(MI0) + mi][(NI0) + ni], 0, 0, 0);          \
    __builtin_amdgcn_s_setprio(0);                                                    \
  } while (0)

  // prologue: 6 half-tiles in flight; wait for K-tile 0 (4 halves), then
  // pre-read tile 0's first quadrant fragments (av0,bv0).
  stage(0, 0, 0); stage(0, 0, 1); stage(0, 0, 2); stage(0, 0, 3);
  stage(1, 1, 0); stage(1, 1, 1);
  asm volatile("s_waitcnt vmcnt(4)" ::: "memory");
  __builtin_amdgcn_s_barrier();
  readA(0, 0, av0);
  readB(0, 0, bv0);

  // main loop. Per phase: issue NEXT-phase ds_reads (retire under this phase's
  // QUAD), stage one half-tile, barrier, QUAD, barrier. vmcnt(4) once per
  // K-tile at P4 drains tile t+1 exactly (leaves A0/A1(t+2) in flight); the
  // post-barrier reads av0/bv0 pull tile t+1's first fragments so Q1 of iter
  // t+1 starts with data already in registers.
#pragma unroll 2
  for (int t = 0; t < NT - 2; ++t) {
    int cur = t & 1, nxt = cur ^ 1;
    // P1: Q1(av0,bv0) [read at t-1 P4]; reads av1; stages B0(t+1)
    readA(cur, 1, av1);
    stage(nxt, t + 1, 2);
    __builtin_amdgcn_s_barrier();
    QUAD(av0, bv0, 0, 0);
    __builtin_amdgcn_s_barrier();
    // P2: Q2(av1,bv0); reads bv1; stages B1(t+1)
    readB(cur, 1, bv1);
    stage(nxt, t + 1, 3);
    __builtin_amdgcn_s_barrier();
    QUAD(av1, bv0, 4, 0);
    __builtin_amdgcn_s_barrier();
    // P3: Q3(av0,bv1); stages A0(t+2) into live buffer (A reads done: av1@P1)
    stage(cur, t + 2, 0);
    __builtin_amdgcn_s_barrier();
    QUAD(av0, bv1, 0, 2);
    __builtin_amdgcn_s_barrier();
    // P4: stages A1(t+2); vmcnt(4) drains tile t+1; post-barrier read
    // av0',bv0' (tile t+1) into now-dead regs, retiring under Q4's MFMAs.
    stage(cur, t + 2, 1);
    asm volatile("s_waitcnt vmcnt(4)" ::: "memory");
    __builtin_amdgcn_s_barrier();
    readA(nxt, 0, av0);
    readB(nxt, 0, bv0);
    QUAD(av1, bv1, 4, 2);
    __builtin_amdgcn_s_barrier();
  }
  // t = NT-2: stage only B(NT-1); full drain at P4
  {
    const int cur = (NT - 2) & 1, nxt = cur ^ 1;
    readA(cur, 1, av1);
    stage(nxt, NT - 1, 2);
    __builtin_amdgcn_s_barrier();
    QUAD(av0, bv0, 0, 0);
    __builtin_amdgcn_s_barrier();
    readB(cur, 1, bv1);
    stage(nxt, NT - 1, 3);
    __builtin_amdgcn_s_barrier();
    QUAD(av1, bv0, 4, 0);
    __builtin_amdgcn_s_barrier();
    __builtin_amdgcn_s_barrier();
    QUAD(av0, bv1, 0, 2);
    __builtin_amdgcn_s_barrier();
    asm volatile("s_waitcnt vmcnt(0)" ::: "memory");
    __builtin_amdgcn_s_barrier();
    readA(nxt, 0, av0);
    readB(nxt, 0, bv0);
    QUAD(av1, bv1, 4, 2);
    __builtin_amdgcn_s_barrier();
  }
  // t = NT-1: all data resident, no stages -> dependency-ordered, no barriers
  {
    const int cur = (NT - 1) & 1;
    readA(cur, 1, av1);
    QUAD(av0, bv0, 0, 0);
    readB(cur, 1, bv1);
    QUAD(av1, bv0, 4, 0);
    QUAD(av0, bv1, 0, 2);
    QUAD(av1, bv1, 4, 2);
  }
#undef QUAD

  // epilogue: D layout col = lane&15, row = (lane>>4)*4 + j
#pragma unroll
  for (int mi = 0; mi < 8; ++mi) {
#pragma unroll
    for (int ni = 0; ni < 4; ++ni) {
      size_t row = m0 + wm * 128 + mi * 16 + q * 4;
      size_t col = n0 + wn * 64 + ni * 16 + r16;
#pragma unroll
      for (int j = 0; j < 4; ++j)
        C[(row + j) * Ndim + col] = f2bf(acc[mi][ni][j]);
    }
  }
}

// ---------- tail: bias + group LN + gates + c LN + outputs ----------
__global__ __launch_bounds__(256)
void tail_kernel(const unsigned short* __restrict__ Cc, const float* __restrict__ cin,
                 const float* __restrict__ bias, const float* __restrict__ gamma,
                 const float* __restrict__ beta, const float* __restrict__ cg,
                 const float* __restrict__ cb, float* __restrict__ out) {
  int lane = threadIdx.x & 63;
  int wid = threadIdx.x >> 6;
  int row = blockIdx.x * 4 + wid;     // one wave per row
  const int base = lane * 16;         // 16 columns per lane

  // c values
  const float4* cp = (const float4*)(cin + (size_t)row * Hdim + base);
  float4 c0 = cp[0], c1 = cp[1], c2 = cp[2], c3 = cp[3];
  float cv[16] = {c0.x, c0.y, c0.z, c0.w, c1.x, c1.y, c1.z, c1.w,
                  c2.x, c2.y, c2.z, c2.w, c3.x, c3.y, c3.z, c3.w};

  float accv[16];   // running sig(i)*tanh(j), then new_c
  float ov[16];     // sig(o)

#pragma unroll
  for (int g = 0; g < 4; ++g) {
    const int4* pp = (const int4*)(Cc + (size_t)row * Ndim + g * Hdim + base);
    int4 u0 = pp[0], u1 = pp[1];
    float vals[16];
    {
      int uu[8] = {u0.x, u0.y, u0.z, u0.w, u1.x, u1.y, u1.z, u1.w};
#pragma unroll
      for (int i = 0; i < 8; ++i) {
        vals[2 * i]     = bf2f((unsigned short)(uu[i] & 0xffff));
        vals[2 * i + 1] = bf2f((unsigned short)(((unsigned)uu[i]) >> 16));
      }
    }
    const float* bp = bias + g * Hdim + base;
#pragma unroll
    for (int t = 0; t < 16; ++t) vals[t] += bp[t];
    float s = 0.f, ss = 0.f;
#pragma unroll
    for (int t = 0; t < 16; ++t) { s += vals[t]; ss += vals[t] * vals[t]; }
#pragma unroll
    for (int off = 32; off; off >>= 1) { s += __shfl_xor(s, off); ss += __shfl_xor(ss, off); }
    float mean = s * (1.f / 1024.f);
    float rstd = rsqrtf(ss * (1.f / 1024.f) - mean * mean + 1e-3f);
    const float* gp = gamma + g * Hdim + base;
    const float* bb = beta + g * Hdim + base;
    if (g == 0) {
#pragma unroll
      for (int t = 0; t < 16; ++t)
        accv[t] = sigmoidf_((vals[t] - mean) * rstd * gp[t] + bb[t]);
    } else if (g == 1) {
#pragma unroll
      for (int t = 0; t < 16; ++t)
        accv[t] *= tanhf_((vals[t] - mean) * rstd * gp[t] + bb[t]);
    } else if (g == 2) {
#pragma unroll
      for (int t = 0; t < 16; ++t)
        accv[t] = cv[t] * sigmoidf_((vals[t] - mean) * rstd * gp[t] + bb[t] + 1.f) + accv[t];
    } else {
#pragma unroll
      for (int t = 0; t < 16; ++t)
        ov[t] = sigmoidf_((vals[t] - mean) * rstd * gp[t] + bb[t]);
    }
  }

  // LN over new_c (accv)
  float s = 0.f, ss = 0.f;
#pragma unroll
  for (int t = 0; t < 16; ++t) { s += accv[t]; ss += accv[t] * accv[t]; }
#pragma unroll
  for (int off = 32; off; off >>= 1) { s += __shfl_xor(s, off); ss += __shfl_xor(ss, off); }
  float mean = s * (1.f / 1024.f);
  float rstd = rsqrtf(ss * (1.f / 1024.f) - mean * mean + 1e-3f);

  const float* cgp = cg + base;
  const float* cbp = cb + base;
  float hv[16];
#pragma unroll
  for (int t = 0; t < 16; ++t) {
    float cl = (accv[t] - mean) * rstd * cgp[t] + cbp[t];
    hv[t] = tanhf_(cl) * ov[t];
  }

  float4* oh = (float4*)(out + (size_t)row * Hdim + base);
  float4* oc = (float4*)(out + (size_t)Mdim * Hdim + (size_t)row * Hdim + base);
#pragma unroll
  for (int v = 0; v < 4; ++v) {
    oh[v] = make_float4(hv[4 * v], hv[4 * v + 1], hv[4 * v + 2], hv[4 * v + 3]);
    oc[v] = make_float4(accv[4 * v], accv[4 * v + 1], accv[4 * v + 2], accv[4 * v + 3]);
  }
}

extern "C" void kernel_launch(void* const* d_in, const int* in_sizes, int n_in,
                              void* d_out, int out_size, void* d_ws, size_t ws_size,
                              hipStream_t stream) {
  const float* x    = (const float*)d_in[0];
  const float* c    = (const float*)d_in[1];
  const float* h    = (const float*)d_in[2];
  const float* Wxh  = (const float*)d_in[3];
  const float* Whh  = (const float*)d_in[4];
  const float* bias = (const float*)d_in[5];
  const float* lng  = (const float*)d_in[6];
  const float* lnb  = (const float*)d_in[7];
  const float* cg   = (const float*)d_in[8];
  const float* cb   = (const float*)d_in[9];
  float* out = (float*)d_out;

  // workspace layout (needs 117,440,512 B):
  unsigned short* Abf = (unsigned short*)d_ws;                  // 8192*2048 bf16 = 32 MiB
  unsigned short* Wt  = Abf + (size_t)Mdim * Kdim;              // 4096*2048 bf16 = 16 MiB
  unsigned short* Cc  = Wt  + (size_t)Ndim * Kdim;              // 8192*4096 bf16 = 64 MiB

  conv_a_kernel<<<8192, 256, 0, stream>>>(x, h, Abf);
  conv_w_kernel<<<dim3(Kdim / 32, Ndim / 32), 256, 0, stream>>>(Wxh, Whh, Wt);
  gemm_kernel<<<(Mdim / BM) * (Ndim / BN), 512, 0, stream>>>(Abf, Wt, Cc);
  tail_kernel<<<Mdim / 4, 256, 0, stream>>>(Cc, c, bias, lng, lnb, cg, cb, out);
}

// Round 5
// 228.985 us; speedup vs baseline: 1.1013x; 1.1013x over previous
//
#include <hip/hip_runtime.h>
#include <stdint.h>

#define Mdim 8192
#define Ndim 4096
#define Kdim 2048
#define Hdim 1024

typedef __attribute__((ext_vector_type(8))) short bf16x8;
typedef __attribute__((ext_vector_type(4))) float f32x4;
typedef __attribute__((ext_vector_type(16))) float f32x16;

__device__ __forceinline__ unsigned short f2bf(float f) {
  union { float f; unsigned u; } v; v.f = f;
  unsigned u = v.u + 0x7fffu + ((v.u >> 16) & 1u);
  return (unsigned short)(u >> 16);
}
__device__ __forceinline__ float bf2f(unsigned short s) {
  union { unsigned u; float f; } v; v.u = ((unsigned)s) << 16;
  return v.f;
}
__device__ __forceinline__ float sigmoidf_(float x) { return 1.f / (1.f + __expf(-x)); }
__device__ __forceinline__ float tanhf_(float x) { return 1.f - 2.f / (1.f + __expf(2.f * x)); }

// ---------- fused pack: [x|h] -> bf16 A[M][K]  and  [Wxh;Whh]^T -> bf16 Wt[N][K] ----------
__global__ void pack_kernel(const float* __restrict__ x, const float* __restrict__ h,
                            const float* __restrict__ Wxh, const float* __restrict__ Whh,
                            unsigned short* __restrict__ A, unsigned short* __restrict__ Wt) {
  if (blockIdx.x < 8192) {
    // conv_a body (unchanged)
    int idx = blockIdx.x * 256 + threadIdx.x;
    int m = idx >> 8;
    int k = (idx & 255) * 8;
    const float* src = (k < Hdim) ? (x + (size_t)m * Hdim + k)
                                  : (h + (size_t)m * Hdim + (k - Hdim));
    float4 a = ((const float4*)src)[0];
    float4 b = ((const float4*)src)[1];
    union { unsigned short s[8]; int4 v; } o;
    o.s[0] = f2bf(a.x); o.s[1] = f2bf(a.y); o.s[2] = f2bf(a.z); o.s[3] = f2bf(a.w);
    o.s[4] = f2bf(b.x); o.s[5] = f2bf(b.y); o.s[6] = f2bf(b.z); o.s[7] = f2bf(b.w);
    *(int4*)(A + (size_t)idx * 8) = o.v;
    return;
  }
  // conv_w body (unchanged; grid flattened: 64 k-tiles x 128 n-tiles)
  __shared__ float tile[32][33];
  int b2 = blockIdx.x - 8192;
  int k0 = (b2 & 63) * 32;
  int n0 = (b2 >> 6) * 32;
  int tx = threadIdx.x & 31, ty = threadIdx.x >> 5;  // 32 x 8
#pragma unroll
  for (int i = 0; i < 32; i += 8) {
    int k = k0 + ty + i;
    float v = (k < Hdim) ? Wxh[(size_t)k * Ndim + n0 + tx]
                         : Whh[(size_t)(k - Hdim) * Ndim + n0 + tx];
    tile[ty + i][tx] = v;
  }
  __syncthreads();
#pragma unroll
  for (int i = 0; i < 32; i += 8) {
    int n = n0 + ty + i;
    Wt[(size_t)n * Kdim + k0 + tx] = f2bf(tile[tx][ty + i]);
  }
}

// ---------- GEMM: C[M][N] (bf16) = A[M][K] * Wt[N][K]^T ----------
// 256x256 tile, BK=64, 8 waves (2M x 4N). Loop/stage/vmcnt schedule = R1/v1
// (measured best; restructures regressed in R2/R4). v5: MFMA shape switched
// 16x16x32 -> 32x32x16 (4060 vs 3378 FLOP/cyc/CU, m119) — identical LDS
// layout/traffic/phases, half the MFMA instruction count, same 128 acc regs.
#define BM 256
#define BN 256
#define BK 64
#define NT (Kdim / BK)   // 32

__global__ __launch_bounds__(512, 2)
void gemm_kernel(const unsigned short* __restrict__ A, const unsigned short* __restrict__ Bt,
                 unsigned short* __restrict__ C) {
  // [dbuf][A/B][256 rows x 64 bf16] = 128 KiB
  __shared__ unsigned short lds[2][2][BM * BK];
  const int tid = threadIdx.x;
  int bid = blockIdx.x;
  int id = (bid & 7) * 64 + (bid >> 3);      // XCD swizzle (512 % 8 == 0, bijective)
  int mT = id >> 4, nT = id & 15;            // 32 x 16 tiles
  size_t m0 = (size_t)mT * BM, n0 = (size_t)nT * BN;
  const int lane = tid & 63, w = tid >> 6;
  const int wm = w >> 2, wn = w & 3;         // 2x4 waves -> 128x64 output each
  const int r32 = lane & 31, q2 = lane >> 5; // 32x32 fragment coords

  const unsigned short* gA = A + m0 * Kdim;
  const unsigned short* gB = Bt + n0 * Kdim;

  // stage one half-tile (region: 0=A rows0-127, 1=A rows128-255, 2=B0, 3=B1).
  // LDS dest is linear (wave-uniform base + lane*16); the slot swizzle
  // stored_slot = logical_slot ^ (row&7) is applied on the GLOBAL source.
  auto stage = [&](int b, int kt, int region) {
    const int mat = region >> 1, half = region & 1;
    const unsigned short* g = mat ? gB : gA;
#pragma unroll
    for (int it = 0; it < 2; ++it) {
      int c = it * 512 + tid;                // 1024 chunks of 16 B per half-tile
      int rr = c >> 3, ss = c & 7;
      __builtin_amdgcn_global_load_lds(
          (const __attribute__((address_space(1))) void*)(
              g + (size_t)(half * 128 + rr) * Kdim + kt * BK + ((ss ^ (rr & 7)) << 3)),
          (__attribute__((address_space(3))) void*)(&lds[b][mat][half * (128 * BK) + c * 8]),
          16, 0, 0);
    }
  };

  // acc[mf][nf]: 4 m-frags x 2 n-frags of 32x32, 16 f32 each = 128 regs total
  f32x16 acc[4][2] = {};
  // fragments: A lane layout row=lane&31, k = ks*16 + (lane>>5)*8 + e
  bf16x8 av0[2][4], av1[2][4], bv0[4], bv1[4];

  auto readA = [&](int cur, int mh, bf16x8 (&av)[2][4]) {
#pragma unroll
    for (int mf = 0; mf < 2; ++mf) {
      int lr = wm * 128 + mh * 64 + mf * 32 + r32;
      const unsigned short* base = &lds[cur][0][lr * BK];
#pragma unroll
      for (int ks = 0; ks < 4; ++ks)
        av[mf][ks] = *(const bf16x8*)(base + ((((ks << 1) | q2) ^ (lr & 7)) << 3));
    }
  };
  auto readB = [&](int cur, int nh, bf16x8 (&bv)[4]) {
    int lr = wn * 64 + nh * 32 + r32;
    const unsigned short* base = &lds[cur][1][lr * BK];
#pragma unroll
    for (int ks = 0; ks < 4; ++ks)
      bv[ks] = *(const bf16x8*)(base + ((((ks << 1) | q2) ^ (lr & 7)) << 3));
  };

  // one C-quadrant (2 m-frags x 1 n-frag) over full K=64: 8 MFMA, setprio-wrapped
#define QUAD(AV, BV, MI0, NI0)                                                        \
  do {                                                                                \
    __builtin_amdgcn_s_setprio(1);                                                    \
    _Pragma("unroll") for (int mf = 0; mf < 2; ++mf)                                  \
      _Pragma("unroll") for (int ks = 0; ks < 4; ++ks)                                \
        acc[(MI0) + mf][NI0] = __builtin_amdgcn_mfma_f32_32x32x16_bf16(               \
            AV[mf][ks], BV[ks], acc[(MI0) + mf][NI0], 0, 0, 0);                       \
    __builtin_amdgcn_s_setprio(0);                                                    \
  } while (0)

  // prologue: 6 half-tiles in flight, then wait for K-tile 0 (4 halves)
  stage(0, 0, 0); stage(0, 0, 1); stage(0, 0, 2); stage(0, 0, 3);
  stage(1, 1, 0); stage(1, 1, 1);
  asm volatile("s_waitcnt vmcnt(4)" ::: "memory");
  __builtin_amdgcn_s_barrier();

  // main loop: stages of t+1 (B halves) and t+2 (A halves); vmcnt(4) once per K-tile.
  // WAR safety identical to R1: A regions of buf[cur] consumed by end of P2;
  // B regions of buf[nxt] last read in K-tile t-1's P3.
#pragma unroll 2
  for (int t = 0; t < NT - 2; ++t) {
    int cur = t & 1, nxt = cur ^ 1;
    // P1: reads av0 (8) + bv0 (4); stages B0(t+1)
    readA(cur, 0, av0);
    readB(cur, 0, bv0);
    stage(nxt, t + 1, 2);
    __builtin_amdgcn_s_barrier();
    QUAD(av0, bv0, 0, 0);
    __builtin_amdgcn_s_barrier();
    // P2: reads av1 (8); stages B1(t+1)
    readA(cur, 1, av1);
    stage(nxt, t + 1, 3);
    __builtin_amdgcn_s_barrier();
    QUAD(av1, bv0, 2, 0);
    __builtin_amdgcn_s_barrier();
    // P3: reads bv1 (4); stages A0(t+2) into the live buffer (A reads done at P2)
    readB(cur, 1, bv1);
    stage(cur, t + 2, 0);
    __builtin_amdgcn_s_barrier();
    QUAD(av1, bv1, 2, 1);
    __builtin_amdgcn_s_barrier();
    // P4: stages A1(t+2); counted wait — leaves A0/A1(t+2) (4 loads) in flight
    stage(cur, t + 2, 1);
    asm volatile("s_waitcnt vmcnt(4)" ::: "memory");
    __builtin_amdgcn_s_barrier();
    QUAD(av0, bv1, 0, 1);
    __builtin_amdgcn_s_barrier();
  }
  // t = NT-2: no t+2 to stage; drain fully for the last K-tile
  {
    const int cur = (NT - 2) & 1, nxt = cur ^ 1;
    readA(cur, 0, av0);
    readB(cur, 0, bv0);
    stage(nxt, NT - 1, 2);
    __builtin_amdgcn_s_barrier();
    QUAD(av0, bv0, 0, 0);
    __builtin_amdgcn_s_barrier();
    readA(cur, 1, av1);
    stage(nxt, NT - 1, 3);
    __builtin_amdgcn_s_barrier();
    QUAD(av1, bv0, 2, 0);
    __builtin_amdgcn_s_barrier();
    readB(cur, 1, bv1);
    __builtin_amdgcn_s_barrier();
    QUAD(av1, bv1, 2, 1);
    __builtin_amdgcn_s_barrier();
    asm volatile("s_waitcnt vmcnt(0)" ::: "memory");
    __builtin_amdgcn_s_barrier();
    QUAD(av0, bv1, 0, 1);
    __builtin_amdgcn_s_barrier();
  }
  // t = NT-1: all data resident, no stages -> no barriers needed
  {
    const int cur = (NT - 1) & 1;
    readA(cur, 0, av0);
    readB(cur, 0, bv0);
    QUAD(av0, bv0, 0, 0);
    readA(cur, 1, av1);
    QUAD(av1, bv0, 2, 0);
    readB(cur, 1, bv1);
    QUAD(av1, bv1, 2, 1);
    QUAD(av0, bv1, 0, 1);
  }
#undef QUAD

  // epilogue: 32x32 D layout (m74/m101): col = lane&31,
  // row = (reg&3) + 8*(reg>>2) + 4*(lane>>5)
#pragma unroll
  for (int mf = 0; mf < 4; ++mf) {
#pragma unroll
    for (int nf = 0; nf < 2; ++nf) {
      size_t rb = m0 + wm * 128 + mf * 32 + q2 * 4;
      size_t col = n0 + wn * 64 + nf * 32 + r32;
#pragma unroll
      for (int reg = 0; reg < 16; ++reg) {
        size_t row = rb + (reg & 3) + 8 * (reg >> 2);
        C[row * Ndim + col] = f2bf(acc[mf][nf][reg]);
      }
    }
  }
}

// ---------- tail: bias + group LN + gates + c LN + outputs ----------
__global__ __launch_bounds__(256)
void tail_kernel(const unsigned short* __restrict__ Cc, const float* __restrict__ cin,
                 const float* __restrict__ bias, const float* __restrict__ gamma,
                 const float* __restrict__ beta, const float* __restrict__ cg,
                 const float* __restrict__ cb, float* __restrict__ out) {
  int lane = threadIdx.x & 63;
  int wid = threadIdx.x >> 6;
  int row = blockIdx.x * 4 + wid;     // one wave per row
  const int base = lane * 16;         // 16 columns per lane

  // c values
  const float4* cp = (const float4*)(cin + (size_t)row * Hdim + base);
  float4 c0 = cp[0], c1 = cp[1], c2 = cp[2], c3 = cp[3];
  float cv[16] = {c0.x, c0.y, c0.z, c0.w, c1.x, c1.y, c1.z, c1.w,
                  c2.x, c2.y, c2.z, c2.w, c3.x, c3.y, c3.z, c3.w};

  float accv[16];   // running sig(i)*tanh(j), then new_c
  float ov[16];     // sig(o)

#pragma unroll
  for (int g = 0; g < 4; ++g) {
    const int4* pp = (const int4*)(Cc + (size_t)row * Ndim + g * Hdim + base);
    int4 u0 = pp[0], u1 = pp[1];
    float vals[16];
    {
      int uu[8] = {u0.x, u0.y, u0.z, u0.w, u1.x, u1.y, u1.z, u1.w};
#pragma unroll
      for (int i = 0; i < 8; ++i) {
        vals[2 * i]     = bf2f((unsigned short)(uu[i] & 0xffff));
        vals[2 * i + 1] = bf2f((unsigned short)(((unsigned)uu[i]) >> 16));
      }
    }
    const float* bp = bias + g * Hdim + base;
#pragma unroll
    for (int t = 0; t < 16; ++t) vals[t] += bp[t];
    float s = 0.f, ss = 0.f;
#pragma unroll
    for (int t = 0; t < 16; ++t) { s += vals[t]; ss += vals[t] * vals[t]; }
#pragma unroll
    for (int off = 32; off; off >>= 1) { s += __shfl_xor(s, off); ss += __shfl_xor(ss, off); }
    float mean = s * (1.f / 1024.f);
    float rstd = rsqrtf(ss * (1.f / 1024.f) - mean * mean + 1e-3f);
    const float* gp = gamma + g * Hdim + base;
    const float* bb = beta + g * Hdim + base;
    if (g == 0) {
#pragma unroll
      for (int t = 0; t < 16; ++t)
        accv[t] = sigmoidf_((vals[t] - mean) * rstd * gp[t] + bb[t]);
    } else if (g == 1) {
#pragma unroll
      for (int t = 0; t < 16; ++t)
        accv[t] *= tanhf_((vals[t] - mean) * rstd * gp[t] + bb[t]);
    } else if (g == 2) {
#pragma unroll
      for (int t = 0; t < 16; ++t)
        accv[t] = cv[t] * sigmoidf_((vals[t] - mean) * rstd * gp[t] + bb[t] + 1.f) + accv[t];
    } else {
#pragma unroll
      for (int t = 0; t < 16; ++t)
        ov[t] = sigmoidf_((vals[t] - mean) * rstd * gp[t] + bb[t]);
    }
  }

  // LN over new_c (accv)
  float s = 0.f, ss = 0.f;
#pragma unroll
  for (int t = 0; t < 16; ++t) { s += accv[t]; ss += accv[t] * accv[t]; }
#pragma unroll
  for (int off = 32; off; off >>= 1) { s += __shfl_xor(s, off); ss += __shfl_xor(ss, off); }
  float mean = s * (1.f / 1024.f);
  float rstd = rsqrtf(ss * (1.f / 1024.f) - mean * mean + 1e-3f);

  const float* cgp = cg + base;
  const float* cbp = cb + base;
  float hv[16];
#pragma unroll
  for (int t = 0; t < 16; ++t) {
    float cl = (accv[t] - mean) * rstd * cgp[t] + cbp[t];
    hv[t] = tanhf_(cl) * ov[t];
  }

  float4* oh = (float4*)(out + (size_t)row * Hdim + base);
  float4* oc = (float4*)(out + (size_t)Mdim * Hdim + (size_t)row * Hdim + base);
#pragma unroll
  for (int v = 0; v < 4; ++v) {
    oh[v] = make_float4(hv[4 * v], hv[4 * v + 1], hv[4 * v + 2], hv[4 * v + 3]);
    oc[v] = make_float4(accv[4 * v], accv[4 * v + 1], accv[4 * v + 2], accv[4 * v + 3]);
  }
}

extern "C" void kernel_launch(void* const* d_in, const int* in_sizes, int n_in,
                              void* d_out, int out_size, void* d_ws, size_t ws_size,
                              hipStream_t stream) {
  const float* x    = (const float*)d_in[0];
  const float* c    = (const float*)d_in[1];
  const float* h    = (const float*)d_in[2];
  const float* Wxh  = (const float*)d_in[3];
  const float* Whh  = (const float*)d_in[4];
  const float* bias = (const float*)d_in[5];
  const float* lng  = (const float*)d_in[6];
  const float* lnb  = (const float*)d_in[7];
  const float* cg   = (const float*)d_in[8];
  const float* cb   = (const float*)d_in[9];
  float* out = (float*)d_out;

  // workspace layout (needs 117,440,512 B):
  unsigned short* Abf = (unsigned short*)d_ws;                  // 8192*2048 bf16 = 32 MiB
  unsigned short* Wt  = Abf + (size_t)Mdim * Kdim;              // 4096*2048 bf16 = 16 MiB
  unsigned short* Cc  = Wt  + (size_t)Ndim * Kdim;              // 8192*4096 bf16 = 64 MiB

  pack_kernel<<<16384, 256, 0, stream>>>(x, h, Wxh, Whh, Abf, Wt);
  gemm_kernel<<<(Mdim / BM) * (Ndim / BN), 512, 0, stream>>>(Abf, Wt, Cc);
  tail_kernel<<<Mdim / 4, 256, 0, stream>>>(Cc, c, bias, lng, lnb, cg, cb, out);
}

// Round 7
// 214.038 us; speedup vs baseline: 1.1782x; 1.0698x over previous
//
#include <hip/hip_runtime.h>
#include <stdint.h>

#define Mdim 8192
#define Ndim 4096
#define Kdim 2048
#define Hdim 1024

typedef __attribute__((ext_vector_type(8))) short bf16x8;
typedef __attribute__((ext_vector_type(4))) float f32x4;

__device__ __forceinline__ unsigned short f2bf(float f) {
  union { float f; unsigned u; } v; v.f = f;
  unsigned u = v.u + 0x7fffu + ((v.u >> 16) & 1u);
  return (unsigned short)(u >> 16);
}
__device__ __forceinline__ float bf2f(unsigned short s) {
  union { unsigned u; float f; } v; v.u = ((unsigned)s) << 16;
  return v.f;
}
__device__ __forceinline__ float sigmoidf_(float x) { return 1.f / (1.f + __expf(-x)); }
__device__ __forceinline__ float tanhf_(float x) { return 1.f - 2.f / (1.f + __expf(2.f * x)); }

// ---------- fused pack: [x|h] -> bf16 A[M][K]  and  [Wxh;Whh]^T -> bf16 Wt[N][K] ----------
__global__ void pack_kernel(const float* __restrict__ x, const float* __restrict__ h,
                            const float* __restrict__ Wxh, const float* __restrict__ Whh,
                            unsigned short* __restrict__ A, unsigned short* __restrict__ Wt) {
  if (blockIdx.x < 8192) {
    int idx = blockIdx.x * 256 + threadIdx.x;
    int m = idx >> 8;
    int k = (idx & 255) * 8;
    const float* src = (k < Hdim) ? (x + (size_t)m * Hdim + k)
                                  : (h + (size_t)m * Hdim + (k - Hdim));
    float4 a = ((const float4*)src)[0];
    float4 b = ((const float4*)src)[1];
    union { unsigned short s[8]; int4 v; } o;
    o.s[0] = f2bf(a.x); o.s[1] = f2bf(a.y); o.s[2] = f2bf(a.z); o.s[3] = f2bf(a.w);
    o.s[4] = f2bf(b.x); o.s[5] = f2bf(b.y); o.s[6] = f2bf(b.z); o.s[7] = f2bf(b.w);
    *(int4*)(A + (size_t)idx * 8) = o.v;
    return;
  }
  __shared__ float tile[32][33];
  int b2 = blockIdx.x - 8192;
  int k0 = (b2 & 63) * 32;
  int n0 = (b2 >> 6) * 32;
  int tx = threadIdx.x & 31, ty = threadIdx.x >> 5;  // 32 x 8
#pragma unroll
  for (int i = 0; i < 32; i += 8) {
    int k = k0 + ty + i;
    float v = (k < Hdim) ? Wxh[(size_t)k * Ndim + n0 + tx]
                         : Whh[(size_t)(k - Hdim) * Ndim + n0 + tx];
    tile[ty + i][tx] = v;
  }
  __syncthreads();
#pragma unroll
  for (int i = 0; i < 32; i += 8) {
    int n = n0 + ty + i;
    Wt[(size_t)n * Kdim + k0 + tx] = f2bf(tile[tx][ty + i]);
  }
}

// ---------- GEMM: C[M][N] (bf16) = A[M][K] * Wt[N][K]^T ----------
// 256x256 tile, BK=64, 8 waves (2M x 4N), 16x16x32 MFMA (best measured shape).
// v7 = v6 with the dropped-stage bug fixed: the t=NT-2 epilogue block must
// stage B0,B1(NT-1) at its P1 (main loop stages B(t+1) inside iter t; v6's
// epilogue skipped it -> last K-tile's B was stale -> absmax 0.77).
// Schedule: software-pipelined ds_reads — each phase issues the NEXT quad's
// reads so their LDS drain hides under this quad's MFMA block. Quad order
// Q1(av0,bv0) Q2(av1,bv0) Q3(av0,bv1) Q4(av1,bv1); av0/bv0 die before their
// replacements are read at P4 -> peak fragment live set unchanged (96 regs).
// vmcnt(2) at end-P3 retires tile t+1 exactly (op accounting: 4 carried +
// 4 @P1 + 2 @P3 = 10; wait-to-2 retires the 8 oldest = tile t+1).
#define BM 256
#define BN 256
#define BK 64
#define NT (Kdim / BK)   // 32

__global__ __launch_bounds__(512, 2)
void gemm_kernel(const unsigned short* __restrict__ A, const unsigned short* __restrict__ Bt,
                 unsigned short* __restrict__ C) {
  __shared__ unsigned short lds[2][2][BM * BK];   // 128 KiB
  const int tid = threadIdx.x;
  int bid = blockIdx.x;
  int id = (bid & 7) * 64 + (bid >> 3);      // XCD swizzle (512 % 8 == 0, bijective)
  int mT = id >> 4, nT = id & 15;            // 32 x 16 tiles
  size_t m0 = (size_t)mT * BM, n0 = (size_t)nT * BN;
  const int lane = tid & 63, w = tid >> 6;
  const int wm = w >> 2, wn = w & 3;         // 2x4 waves -> 128x64 output each
  const int r16 = lane & 15, q = lane >> 4;

  const unsigned short* gA = A + m0 * Kdim;
  const unsigned short* gB = Bt + n0 * Kdim;

  // stage one half-tile (region: 0=A rows0-127, 1=A rows128-255, 2=B0, 3=B1).
  // LDS dest linear; slot swizzle stored_slot = logical_slot ^ (row&7) applied
  // on the GLOBAL source (rule #21).
  auto stage = [&](int b, int kt, int region) {
    const int mat = region >> 1, half = region & 1;
    const unsigned short* g = mat ? gB : gA;
#pragma unroll
    for (int it = 0; it < 2; ++it) {
      int c = it * 512 + tid;                // 1024 chunks of 16 B per half-tile
      int rr = c >> 3, ss = c & 7;
      __builtin_amdgcn_global_load_lds(
          (const __attribute__((address_space(1))) void*)(
              g + (size_t)(half * 128 + rr) * Kdim + kt * BK + ((ss ^ (rr & 7)) << 3)),
          (__attribute__((address_space(3))) void*)(&lds[b][mat][half * (128 * BK) + c * 8]),
          16, 0, 0);
    }
  };

  f32x4 acc[8][4] = {};
  bf16x8 av0[4][2], av1[4][2], bv0[2][2], bv1[2][2];

  auto readA = [&](int cur, int mh, bf16x8 (&av)[4][2]) {
#pragma unroll
    for (int mi = 0; mi < 4; ++mi) {
      int lr = wm * 128 + mh * 64 + mi * 16 + r16;
      const unsigned short* base = &lds[cur][0][lr * BK];
#pragma unroll
      for (int ks = 0; ks < 2; ++ks)
        av[mi][ks] = *(const bf16x8*)(base + ((((ks << 2) | q) ^ (lr & 7)) << 3));
    }
  };
  auto readB = [&](int cur, int nh, bf16x8 (&bv)[2][2]) {
#pragma unroll
    for (int ni = 0; ni < 2; ++ni) {
      int lr = wn * 64 + nh * 32 + ni * 16 + r16;
      const unsigned short* base = &lds[cur][1][lr * BK];
#pragma unroll
      for (int ks = 0; ks < 2; ++ks)
        bv[ni][ks] = *(const bf16x8*)(base + ((((ks << 2) | q) ^ (lr & 7)) << 3));
    }
  };

#define QUAD(AV, BV, MI0, NI0)                                                        \
  do {                                                                                \
    __builtin_amdgcn_s_setprio(1);                                                    \
    _Pragma("unroll") for (int mi = 0; mi < 4; ++mi)                                  \
      _Pragma("unroll") for (int ni = 0; ni < 2; ++ni)                                \
        _Pragma("unroll") for (int ks = 0; ks < 2; ++ks)                              \
          acc[(MI0) + mi][(NI0) + ni] = __builtin_amdgcn_mfma_f32_16x16x32_bf16(      \
              AV[mi][ks], BV[ni][ks], acc[(MI0) + mi][(NI0) + ni], 0, 0, 0);          \
    __builtin_amdgcn_s_setprio(0);                                                    \
  } while (0)

  // prologue: tile0 fully staged + A halves of tile1; retire tile0 (vmcnt(4)
  // = 4 ops = A0,A1(tile1) left in flight), pre-read tile0's first quad.
  // Loop invariant entering iter t: tile t resident in buf[cur]; av0/bv0(t)
  // in regs; in-flight = {A0(t+1), A1(t+1)} (4 ops).
  stage(0, 0, 0); stage(0, 0, 1); stage(0, 0, 2); stage(0, 0, 3);
  stage(1, 1, 0); stage(1, 1, 1);
  asm volatile("s_waitcnt vmcnt(4)" ::: "memory");
  __builtin_amdgcn_s_barrier();
  readA(0, 0, av0);
  readB(0, 0, bv0);

#pragma unroll 1
  for (int t = 0; t < NT - 2; ++t) {
    int cur = t & 1, nxt = cur ^ 1;
    // P1: reads av1 (retires under Q1); stages B0,B1(t+1)
    readA(cur, 1, av1);
    stage(nxt, t + 1, 2);
    stage(nxt, t + 1, 3);
    __builtin_amdgcn_s_barrier();
    QUAD(av0, bv0, 0, 0);                    // Q1
    __builtin_amdgcn_s_barrier();
    // P2: reads bv1 (retires under Q2)
    readB(cur, 1, bv1);
    __builtin_amdgcn_s_barrier();
    QUAD(av1, bv0, 4, 0);                    // Q2 (bv0 dies)
    __builtin_amdgcn_s_barrier();
    // P3: stages A0(t+2) into live buffer (A reads of cur done at P1)
    stage(cur, t + 2, 0);
    __builtin_amdgcn_s_barrier();
    QUAD(av0, bv1, 0, 2);                    // Q3 (av0 dies)
    // retire tile t+1 (10 ops out; wait-to-2 retires A0A1,B0B1(t+1))
    asm volatile("s_waitcnt vmcnt(2)" ::: "memory");
    __builtin_amdgcn_s_barrier();
    // P4: read tile t+1's first quad into freed regs (retires under Q4);
    // stage A1(t+2)
    readA(nxt, 0, av0);
    readB(nxt, 0, bv0);
    stage(cur, t + 2, 1);
    __builtin_amdgcn_s_barrier();
    QUAD(av1, bv1, 4, 2);                    // Q4
    __builtin_amdgcn_s_barrier();
  }
  // t = NT-2: mirror of main-loop iter but no t+2 stages; B(NT-1) staged at
  // P1 (the v6 bug: these two stages were missing); full drain at end-P3.
  {
    const int cur = (NT - 2) & 1, nxt = cur ^ 1;
    readA(cur, 1, av1);
    stage(nxt, NT - 1, 2);
    stage(nxt, NT - 1, 3);
    __builtin_amdgcn_s_barrier();
    QUAD(av0, bv0, 0, 0);
    __builtin_amdgcn_s_barrier();
    readB(cur, 1, bv1);
    __builtin_amdgcn_s_barrier();
    QUAD(av1, bv0, 4, 0);
    __builtin_amdgcn_s_barrier();
    QUAD(av0, bv1, 0, 2);
    asm volatile("s_waitcnt vmcnt(0)" ::: "memory");   // tile NT-1 resident
    __builtin_amdgcn_s_barrier();
    readA(nxt, 0, av0);
    readB(nxt, 0, bv0);
    __builtin_amdgcn_s_barrier();
    QUAD(av1, bv1, 4, 2);
    __builtin_amdgcn_s_barrier();
  }
  // t = NT-1: all resident, no stages -> dependency-ordered only
  {
    const int cur = (NT - 1) & 1;
    readA(cur, 1, av1);
    QUAD(av0, bv0, 0, 0);
    readB(cur, 1, bv1);
    QUAD(av1, bv0, 4, 0);
    QUAD(av0, bv1, 0, 2);
    QUAD(av1, bv1, 4, 2);
  }
#undef QUAD

  // epilogue: D layout col = lane&15, row = (lane>>4)*4 + j
#pragma unroll
  for (int mi = 0; mi < 8; ++mi) {
#pragma unroll
    for (int ni = 0; ni < 4; ++ni) {
      size_t row = m0 + wm * 128 + mi * 16 + q * 4;
      size_t col = n0 + wn * 64 + ni * 16 + r16;
#pragma unroll
      for (int j = 0; j < 4; ++j)
        C[(row + j) * Ndim + col] = f2bf(acc[mi][ni][j]);
    }
  }
}

// ---------- tail: bias + group LN + gates + c LN + outputs ----------
__global__ __launch_bounds__(256)
void tail_kernel(const unsigned short* __restrict__ Cc, const float* __restrict__ cin,
                 const float* __restrict__ bias, const float* __restrict__ gamma,
                 const float* __restrict__ beta, const float* __restrict__ cg,
                 const float* __restrict__ cb, float* __restrict__ out) {
  int lane = threadIdx.x & 63;
  int wid = threadIdx.x >> 6;
  int row = blockIdx.x * 4 + wid;     // one wave per row
  const int base = lane * 16;         // 16 columns per lane

  const float4* cp = (const float4*)(cin + (size_t)row * Hdim + base);
  float4 c0 = cp[0], c1 = cp[1], c2 = cp[2], c3 = cp[3];
  float cv[16] = {c0.x, c0.y, c0.z, c0.w, c1.x, c1.y, c1.z, c1.w,
                  c2.x, c2.y, c2.z, c2.w, c3.x, c3.y, c3.z, c3.w};

  float accv[16];   // running sig(i)*tanh(j), then new_c
  float ov[16];     // sig(o)

#pragma unroll
  for (int g = 0; g < 4; ++g) {
    const int4* pp = (const int4*)(Cc + (size_t)row * Ndim + g * Hdim + base);
    int4 u0 = pp[0], u1 = pp[1];
    float vals[16];
    {
      int uu[8] = {u0.x, u0.y, u0.z, u0.w, u1.x, u1.y, u1.z, u1.w};
#pragma unroll
      for (int i = 0; i < 8; ++i) {
        vals[2 * i]     = bf2f((unsigned short)(uu[i] & 0xffff));
        vals[2 * i + 1] = bf2f((unsigned short)(((unsigned)uu[i]) >> 16));
      }
    }
    const float* bp = bias + g * Hdim + base;
#pragma unroll
    for (int t = 0; t < 16; ++t) vals[t] += bp[t];
    float s = 0.f, ss = 0.f;
#pragma unroll
    for (int t = 0; t < 16; ++t) { s += vals[t]; ss += vals[t] * vals[t]; }
#pragma unroll
    for (int off = 32; off; off >>= 1) { s += __shfl_xor(s, off); ss += __shfl_xor(ss, off); }
    float mean = s * (1.f / 1024.f);
    float rstd = rsqrtf(ss * (1.f / 1024.f) - mean * mean + 1e-3f);
    const float* gp = gamma + g * Hdim + base;
    const float* bb = beta + g * Hdim + base;
    if (g == 0) {
#pragma unroll
      for (int t = 0; t < 16; ++t)
        accv[t] = sigmoidf_((vals[t] - mean) * rstd * gp[t] + bb[t]);
    } else if (g == 1) {
#pragma unroll
      for (int t = 0; t < 16; ++t)
        accv[t] *= tanhf_((vals[t] - mean) * rstd * gp[t] + bb[t]);
    } else if (g == 2) {
#pragma unroll
      for (int t = 0; t < 16; ++t)
        accv[t] = cv[t] * sigmoidf_((vals[t] - mean) * rstd * gp[t] + bb[t] + 1.f) + accv[t];
    } else {
#pragma unroll
      for (int t = 0; t < 16; ++t)
        ov[t] = sigmoidf_((vals[t] - mean) * rstd * gp[t] + bb[t]);
    }
  }

  float s = 0.f, ss = 0.f;
#pragma unroll
  for (int t = 0; t < 16; ++t) { s += accv[t]; ss += accv[t] * accv[t]; }
#pragma unroll
  for (int off = 32; off; off >>= 1) { s += __shfl_xor(s, off); ss += __shfl_xor(ss, off); }
  float mean = s * (1.f / 1024.f);
  float rstd = rsqrtf(ss * (1.f / 1024.f) - mean * mean + 1e-3f);

  const float* cgp = cg + base;
  const float* cbp = cb + base;
  float hv[16];
#pragma unroll
  for (int t = 0; t < 16; ++t) {
    float cl = (accv[t] - mean) * rstd * cgp[t] + cbp[t];
    hv[t] = tanhf_(cl) * ov[t];
  }

  float4* oh = (float4*)(out + (size_t)row * Hdim + base);
  float4* oc = (float4*)(out + (size_t)Mdim * Hdim + (size_t)row * Hdim + base);
#pragma unroll
  for (int v = 0; v < 4; ++v) {
    oh[v] = make_float4(hv[4 * v], hv[4 * v + 1], hv[4 * v + 2], hv[4 * v + 3]);
    oc[v] = make_float4(accv[4 * v], accv[4 * v + 1], accv[4 * v + 2], accv[4 * v + 3]);
  }
}

extern "C" void kernel_launch(void* const* d_in, const int* in_sizes, int n_in,
                              void* d_out, int out_size, void* d_ws, size_t ws_size,
                              hipStream_t stream) {
  const float* x    = (const float*)d_in[0];
  const float* c    = (const float*)d_in[1];
  const float* h    = (const float*)d_in[2];
  const float* Wxh  = (const float*)d_in[3];
  const float* Whh  = (const float*)d_in[4];
  const float* bias = (const float*)d_in[5];
  const float* lng  = (const float*)d_in[6];
  const float* lnb  = (const float*)d_in[7];
  const float* cg   = (const float*)d_in[8];
  const float* cb   = (const float*)d_in[9];
  float* out = (float*)d_out;

  unsigned short* Abf = (unsigned short*)d_ws;                  // 32 MiB
  unsigned short* Wt  = Abf + (size_t)Mdim * Kdim;              // 16 MiB
  unsigned short* Cc  = Wt  + (size_t)Ndim * Kdim;              // 64 MiB

  pack_kernel<<<16384, 256, 0, stream>>>(x, h, Wxh, Whh, Abf, Wt);
  gemm_kernel<<<(Mdim / BM) * (Ndim / BN), 512, 0, stream>>>(Abf, Wt, Cc);
  tail_kernel<<<Mdim / 4, 256, 0, stream>>>(Cc, c, bias, lng, lnb, cg, cb, out);
}

// Round 8
// 212.794 us; speedup vs baseline: 1.1851x; 1.0058x over previous
//
#include <hip/hip_runtime.h>
#include <stdint.h>

#define Mdim 8192
#define Ndim 4096
#define Kdim 2048
#define Hdim 1024

typedef __attribute__((ext_vector_type(8))) short bf16x8;
typedef __attribute__((ext_vector_type(4))) float f32x4;

__device__ __forceinline__ unsigned short f2bf(float f) {
  union { float f; unsigned u; } v; v.f = f;
  unsigned u = v.u + 0x7fffu + ((v.u >> 16) & 1u);
  return (unsigned short)(u >> 16);
}
__device__ __forceinline__ float bf2f(unsigned short s) {
  union { unsigned u; float f; } v; v.u = ((unsigned)s) << 16;
  return v.f;
}
__device__ __forceinline__ float sigmoidf_(float x) { return 1.f / (1.f + __expf(-x)); }
__device__ __forceinline__ float tanhf_(float x) { return 1.f - 2.f / (1.f + __expf(2.f * x)); }

// ---------- fused pack: [x|h] -> bf16 A[M][K]  and  [Wxh;Whh]^T -> bf16 Wt[N][K] ----------
__global__ void pack_kernel(const float* __restrict__ x, const float* __restrict__ h,
                            const float* __restrict__ Wxh, const float* __restrict__ Whh,
                            unsigned short* __restrict__ A, unsigned short* __restrict__ Wt) {
  if (blockIdx.x < 8192) {
    int idx = blockIdx.x * 256 + threadIdx.x;
    int m = idx >> 8;
    int k = (idx & 255) * 8;
    const float* src = (k < Hdim) ? (x + (size_t)m * Hdim + k)
                                  : (h + (size_t)m * Hdim + (k - Hdim));
    float4 a = ((const float4*)src)[0];
    float4 b = ((const float4*)src)[1];
    union { unsigned short s[8]; int4 v; } o;
    o.s[0] = f2bf(a.x); o.s[1] = f2bf(a.y); o.s[2] = f2bf(a.z); o.s[3] = f2bf(a.w);
    o.s[4] = f2bf(b.x); o.s[5] = f2bf(b.y); o.s[6] = f2bf(b.z); o.s[7] = f2bf(b.w);
    *(int4*)(A + (size_t)idx * 8) = o.v;
    return;
  }
  __shared__ float tile[32][33];
  int b2 = blockIdx.x - 8192;
  int k0 = (b2 & 63) * 32;
  int n0 = (b2 >> 6) * 32;
  int tx = threadIdx.x & 31, ty = threadIdx.x >> 5;  // 32 x 8
#pragma unroll
  for (int i = 0; i < 32; i += 8) {
    int k = k0 + ty + i;
    float v = (k < Hdim) ? Wxh[(size_t)k * Ndim + n0 + tx]
                         : Whh[(size_t)(k - Hdim) * Ndim + n0 + tx];
    tile[ty + i][tx] = v;
  }
  __syncthreads();
#pragma unroll
  for (int i = 0; i < 32; i += 8) {
    int n = n0 + ty + i;
    Wt[(size_t)n * Kdim + k0 + tx] = f2bf(tile[tx][ty + i]);
  }
}

// ---------- GEMM: C[M][N] (bf16) = A[M][K] * Wt[N][K]^T ----------
// 256x256 tile, BK=64, 8 waves (2M x 4N), 16x16x32 MFMA.
// v8 = R1's measured-best loop (P1 reads av0+bv0/stage B0(t+1); P2 av1/B1;
// P3 bv1/A0(t+2); P4 -/A1(t+2)+vmcnt(4)) with the m201 template's explicit
// wait placement added (the one un-ported delta):
//   - partial s_waitcnt lgkmcnt(8) BEFORE the P1 barrier (12-read phase)
//   - s_waitcnt lgkmcnt(0) + sched_barrier(0) AFTER each pre-QUAD barrier
// so the ds_read drain happens across the barrier (overlapping other waves'
// MFMA) instead of a compiler-inserted full drain before barrier arrival.
#define BM 256
#define BN 256
#define BK 64
#define NT (Kdim / BK)   // 32

#define LGKM0_SB() do {                                              \
    asm volatile("s_waitcnt lgkmcnt(0)" ::: "memory");               \
    __builtin_amdgcn_sched_barrier(0);                               \
  } while (0)

__global__ __launch_bounds__(512, 2)
void gemm_kernel(const unsigned short* __restrict__ A, const unsigned short* __restrict__ Bt,
                 unsigned short* __restrict__ C) {
  __shared__ unsigned short lds[2][2][BM * BK];   // 128 KiB
  const int tid = threadIdx.x;
  int bid = blockIdx.x;
  int id = (bid & 7) * 64 + (bid >> 3);      // XCD swizzle (512 % 8 == 0, bijective)
  int mT = id >> 4, nT = id & 15;            // 32 x 16 tiles
  size_t m0 = (size_t)mT * BM, n0 = (size_t)nT * BN;
  const int lane = tid & 63, w = tid >> 6;
  const int wm = w >> 2, wn = w & 3;         // 2x4 waves -> 128x64 output each
  const int r16 = lane & 15, q = lane >> 4;

  const unsigned short* gA = A + m0 * Kdim;
  const unsigned short* gB = Bt + n0 * Kdim;

  // stage one half-tile (region: 0=A rows0-127, 1=A rows128-255, 2=B0, 3=B1).
  // LDS dest linear; slot swizzle stored_slot = logical_slot ^ (row&7) applied
  // on the GLOBAL source (rule #21).
  auto stage = [&](int b, int kt, int region) {
    const int mat = region >> 1, half = region & 1;
    const unsigned short* g = mat ? gB : gA;
#pragma unroll
    for (int it = 0; it < 2; ++it) {
      int c = it * 512 + tid;                // 1024 chunks of 16 B per half-tile
      int rr = c >> 3, ss = c & 7;
      __builtin_amdgcn_global_load_lds(
          (const __attribute__((address_space(1))) void*)(
              g + (size_t)(half * 128 + rr) * Kdim + kt * BK + ((ss ^ (rr & 7)) << 3)),
          (__attribute__((address_space(3))) void*)(&lds[b][mat][half * (128 * BK) + c * 8]),
          16, 0, 0);
    }
  };

  f32x4 acc[8][4] = {};
  bf16x8 av0[4][2], av1[4][2], bv0[2][2], bv1[2][2];

  auto readA = [&](int cur, int mh, bf16x8 (&av)[4][2]) {
#pragma unroll
    for (int mi = 0; mi < 4; ++mi) {
      int lr = wm * 128 + mh * 64 + mi * 16 + r16;
      const unsigned short* base = &lds[cur][0][lr * BK];
#pragma unroll
      for (int ks = 0; ks < 2; ++ks)
        av[mi][ks] = *(const bf16x8*)(base + ((((ks << 2) | q) ^ (lr & 7)) << 3));
    }
  };
  auto readB = [&](int cur, int nh, bf16x8 (&bv)[2][2]) {
#pragma unroll
    for (int ni = 0; ni < 2; ++ni) {
      int lr = wn * 64 + nh * 32 + ni * 16 + r16;
      const unsigned short* base = &lds[cur][1][lr * BK];
#pragma unroll
      for (int ks = 0; ks < 2; ++ks)
        bv[ni][ks] = *(const bf16x8*)(base + ((((ks << 2) | q) ^ (lr & 7)) << 3));
    }
  };

#define QUAD(AV, BV, MI0, NI0)                                                        \
  do {                                                                                \
    __builtin_amdgcn_s_setprio(1);                                                    \
    _Pragma("unroll") for (int mi = 0; mi < 4; ++mi)                                  \
      _Pragma("unroll") for (int ni = 0; ni < 2; ++ni)                                \
        _Pragma("unroll") for (int ks = 0; ks < 2; ++ks)                              \
          acc[(MI0) + mi][(NI0) + ni] = __builtin_amdgcn_mfma_f32_16x16x32_bf16(      \
              AV[mi][ks], BV[ni][ks], acc[(MI0) + mi][(NI0) + ni], 0, 0, 0);          \
    __builtin_amdgcn_s_setprio(0);                                                    \
  } while (0)

  // prologue: 6 half-tiles in flight, then wait for K-tile 0 (4 halves)
  stage(0, 0, 0); stage(0, 0, 1); stage(0, 0, 2); stage(0, 0, 3);
  stage(1, 1, 0); stage(1, 1, 1);
  asm volatile("s_waitcnt vmcnt(4)" ::: "memory");
  __builtin_amdgcn_s_barrier();

  // main loop (R1 schedule + template wait placement).
#pragma unroll 1
  for (int t = 0; t < NT - 2; ++t) {
    int cur = t & 1, nxt = cur ^ 1;
    // P1: reads av0 (8) + bv0 (4); stages B0(t+1); partial lgkm drain
    readA(cur, 0, av0);
    readB(cur, 0, bv0);
    stage(nxt, t + 1, 2);
    asm volatile("s_waitcnt lgkmcnt(8)" ::: "memory");
    __builtin_amdgcn_s_barrier();
    LGKM0_SB();
    QUAD(av0, bv0, 0, 0);
    __builtin_amdgcn_s_barrier();
    // P2: reads av1 (8); stages B1(t+1)
    readA(cur, 1, av1);
    stage(nxt, t + 1, 3);
    __builtin_amdgcn_s_barrier();
    LGKM0_SB();
    QUAD(av1, bv0, 4, 0);
    __builtin_amdgcn_s_barrier();
    // P3: reads bv1 (4); stages A0(t+2) into live buffer (A reads done at P2)
    readB(cur, 1, bv1);
    stage(cur, t + 2, 0);
    __builtin_amdgcn_s_barrier();
    LGKM0_SB();
    QUAD(av1, bv1, 4, 2);
    __builtin_amdgcn_s_barrier();
    // P4: stages A1(t+2); vmcnt(4) leaves A0/A1(t+2) in flight
    stage(cur, t + 2, 1);
    asm volatile("s_waitcnt vmcnt(4)" ::: "memory");
    __builtin_amdgcn_s_barrier();
    LGKM0_SB();
    QUAD(av0, bv1, 0, 2);
    __builtin_amdgcn_s_barrier();
  }
  // t = NT-2: no t+2 to stage; drain fully for the last K-tile
  {
    const int cur = (NT - 2) & 1, nxt = cur ^ 1;
    readA(cur, 0, av0);
    readB(cur, 0, bv0);
    stage(nxt, NT - 1, 2);
    asm volatile("s_waitcnt lgkmcnt(8)" ::: "memory");
    __builtin_amdgcn_s_barrier();
    LGKM0_SB();
    QUAD(av0, bv0, 0, 0);
    __builtin_amdgcn_s_barrier();
    readA(cur, 1, av1);
    stage(nxt, NT - 1, 3);
    __builtin_amdgcn_s_barrier();
    LGKM0_SB();
    QUAD(av1, bv0, 4, 0);
    __builtin_amdgcn_s_barrier();
    readB(cur, 1, bv1);
    __builtin_amdgcn_s_barrier();
    LGKM0_SB();
    QUAD(av1, bv1, 4, 2);
    __builtin_amdgcn_s_barrier();
    asm volatile("s_waitcnt vmcnt(0)" ::: "memory");
    __builtin_amdgcn_s_barrier();
    QUAD(av0, bv1, 0, 2);
    __builtin_amdgcn_s_barrier();
  }
  // t = NT-1: all resident, no stages -> dependency-ordered only
  {
    const int cur = (NT - 1) & 1;
    readA(cur, 0, av0);
    readB(cur, 0, bv0);
    QUAD(av0, bv0, 0, 0);
    readA(cur, 1, av1);
    QUAD(av1, bv0, 4, 0);
    readB(cur, 1, bv1);
    QUAD(av1, bv1, 4, 2);
    QUAD(av0, bv1, 0, 2);
  }
#undef QUAD

  // epilogue: D layout col = lane&15, row = (lane>>4)*4 + j
#pragma unroll
  for (int mi = 0; mi < 8; ++mi) {
#pragma unroll
    for (int ni = 0; ni < 4; ++ni) {
      size_t row = m0 + wm * 128 + mi * 16 + q * 4;
      size_t col = n0 + wn * 64 + ni * 16 + r16;
#pragma unroll
      for (int j = 0; j < 4; ++j)
        C[(row + j) * Ndim + col] = f2bf(acc[mi][ni][j]);
    }
  }
}

// ---------- tail: bias + group LN + gates + c LN + outputs ----------
__global__ __launch_bounds__(256)
void tail_kernel(const unsigned short* __restrict__ Cc, const float* __restrict__ cin,
                 const float* __restrict__ bias, const float* __restrict__ gamma,
                 const float* __restrict__ beta, const float* __restrict__ cg,
                 const float* __restrict__ cb, float* __restrict__ out) {
  int lane = threadIdx.x & 63;
  int wid = threadIdx.x >> 6;
  int row = blockIdx.x * 4 + wid;     // one wave per row
  const int base = lane * 16;         // 16 columns per lane

  const float4* cp = (const float4*)(cin + (size_t)row * Hdim + base);
  float4 c0 = cp[0], c1 = cp[1], c2 = cp[2], c3 = cp[3];
  float cv[16] = {c0.x, c0.y, c0.z, c0.w, c1.x, c1.y, c1.z, c1.w,
                  c2.x, c2.y, c2.z, c2.w, c3.x, c3.y, c3.z, c3.w};

  float accv[16];   // running sig(i)*tanh(j), then new_c
  float ov[16];     // sig(o)

#pragma unroll
  for (int g = 0; g < 4; ++g) {
    const int4* pp = (const int4*)(Cc + (size_t)row * Ndim + g * Hdim + base);
    int4 u0 = pp[0], u1 = pp[1];
    float vals[16];
    {
      int uu[8] = {u0.x, u0.y, u0.z, u0.w, u1.x, u1.y, u1.z, u1.w};
#pragma unroll
      for (int i = 0; i < 8; ++i) {
        vals[2 * i]     = bf2f((unsigned short)(uu[i] & 0xffff));
        vals[2 * i + 1] = bf2f((unsigned short)(((unsigned)uu[i]) >> 16));
      }
    }
    const float* bp = bias + g * Hdim + base;
#pragma unroll
    for (int t = 0; t < 16; ++t) vals[t] += bp[t];
    float s = 0.f, ss = 0.f;
#pragma unroll
    for (int t = 0; t < 16; ++t) { s += vals[t]; ss += vals[t] * vals[t]; }
#pragma unroll
    for (int off = 32; off; off >>= 1) { s += __shfl_xor(s, off); ss += __shfl_xor(ss, off); }
    float mean = s * (1.f / 1024.f);
    float rstd = rsqrtf(ss * (1.f / 1024.f) - mean * mean + 1e-3f);
    const float* gp = gamma + g * Hdim + base;
    const float* bb = beta + g * Hdim + base;
    if (g == 0) {
#pragma unroll
      for (int t = 0; t < 16; ++t)
        accv[t] = sigmoidf_((vals[t] - mean) * rstd * gp[t] + bb[t]);
    } else if (g == 1) {
#pragma unroll
      for (int t = 0; t < 16; ++t)
        accv[t] *= tanhf_((vals[t] - mean) * rstd * gp[t] + bb[t]);
    } else if (g == 2) {
#pragma unroll
      for (int t = 0; t < 16; ++t)
        accv[t] = cv[t] * sigmoidf_((vals[t] - mean) * rstd * gp[t] + bb[t] + 1.f) + accv[t];
    } else {
#pragma unroll
      for (int t = 0; t < 16; ++t)
        ov[t] = sigmoidf_((vals[t] - mean) * rstd * gp[t] + bb[t]);
    }
  }

  float s = 0.f, ss = 0.f;
#pragma unroll
  for (int t = 0; t < 16; ++t) { s += accv[t]; ss += accv[t] * accv[t]; }
#pragma unroll
  for (int off = 32; off; off >>= 1) { s += __shfl_xor(s, off); ss += __shfl_xor(ss, off); }
  float mean = s * (1.f / 1024.f);
  float rstd = rsqrtf(ss * (1.f / 1024.f) - mean * mean + 1e-3f);

  const float* cgp = cg + base;
  const float* cbp = cb + base;
  float hv[16];
#pragma unroll
  for (int t = 0; t < 16; ++t) {
    float cl = (accv[t] - mean) * rstd * cgp[t] + cbp[t];
    hv[t] = tanhf_(cl) * ov[t];
  }

  float4* oh = (float4*)(out + (size_t)row * Hdim + base);
  float4* oc = (float4*)(out + (size_t)Mdim * Hdim + (size_t)row * Hdim + base);
#pragma unroll
  for (int v = 0; v < 4; ++v) {
    oh[v] = make_float4(hv[4 * v], hv[4 * v + 1], hv[4 * v + 2], hv[4 * v + 3]);
    oc[v] = make_float4(accv[4 * v], accv[4 * v + 1], accv[4 * v + 2], accv[4 * v + 3]);
  }
}

extern "C" void kernel_launch(void* const* d_in, const int* in_sizes, int n_in,
                              void* d_out, int out_size, void* d_ws, size_t ws_size,
                              hipStream_t stream) {
  const float* x    = (const float*)d_in[0];
  const float* c    = (const float*)d_in[1];
  const float* h    = (const float*)d_in[2];
  const float* Wxh  = (const float*)d_in[3];
  const float* Whh  = (const float*)d_in[4];
  const float* bias = (const float*)d_in[5];
  const float* lng  = (const float*)d_in[6];
  const float* lnb  = (const float*)d_in[7];
  const float* cg   = (const float*)d_in[8];
  const float* cb   = (const float*)d_in[9];
  float* out = (float*)d_out;

  unsigned short* Abf = (unsigned short*)d_ws;                  // 32 MiB
  unsigned short* Wt  = Abf + (size_t)Mdim * Kdim;              // 16 MiB
  unsigned short* Cc  = Wt  + (size_t)Ndim * Kdim;              // 64 MiB

  pack_kernel<<<16384, 256, 0, stream>>>(x, h, Wxh, Whh, Abf, Wt);
  gemm_kernel<<<(Mdim / BM) * (Ndim / BN), 512, 0, stream>>>(Abf, Wt, Cc);
  tail_kernel<<<Mdim / 4, 256, 0, stream>>>(Cc, c, bias, lng, lnb, cg, cb, out);
}

// Round 9
// 209.830 us; speedup vs baseline: 1.2018x; 1.0141x over previous
//
#include <hip/hip_runtime.h>
#include <stdint.h>

#define Mdim 8192
#define Ndim 4096
#define Kdim 2048
#define Hdim 1024

typedef __attribute__((ext_vector_type(8))) short bf16x8;
typedef __attribute__((ext_vector_type(4))) float f32x4;

__device__ __forceinline__ unsigned short f2bf(float f) {
  union { float f; unsigned u; } v; v.f = f;
  unsigned u = v.u + 0x7fffu + ((v.u >> 16) & 1u);
  return (unsigned short)(u >> 16);
}
__device__ __forceinline__ float bf2f(unsigned short s) {
  union { unsigned u; float f; } v; v.u = ((unsigned)s) << 16;
  return v.f;
}
__device__ __forceinline__ float sigmoidf_(float x) { return 1.f / (1.f + __expf(-x)); }
__device__ __forceinline__ float tanhf_(float x) { return 1.f - 2.f / (1.f + __expf(2.f * x)); }

// ---------- fused pack: [x|h] -> bf16 A[M][K]  and  [Wxh;Whh]^T -> bf16 Wt[N][K] ----------
__global__ void pack_kernel(const float* __restrict__ x, const float* __restrict__ h,
                            const float* __restrict__ Wxh, const float* __restrict__ Whh,
                            unsigned short* __restrict__ A, unsigned short* __restrict__ Wt) {
  if (blockIdx.x < 8192) {
    int idx = blockIdx.x * 256 + threadIdx.x;
    int m = idx >> 8;
    int k = (idx & 255) * 8;
    const float* src = (k < Hdim) ? (x + (size_t)m * Hdim + k)
                                  : (h + (size_t)m * Hdim + (k - Hdim));
    float4 a = ((const float4*)src)[0];
    float4 b = ((const float4*)src)[1];
    union { unsigned short s[8]; int4 v; } o;
    o.s[0] = f2bf(a.x); o.s[1] = f2bf(a.y); o.s[2] = f2bf(a.z); o.s[3] = f2bf(a.w);
    o.s[4] = f2bf(b.x); o.s[5] = f2bf(b.y); o.s[6] = f2bf(b.z); o.s[7] = f2bf(b.w);
    *(int4*)(A + (size_t)idx * 8) = o.v;
    return;
  }
  __shared__ float tile[32][33];
  int b2 = blockIdx.x - 8192;
  int k0 = (b2 & 63) * 32;
  int n0 = (b2 >> 6) * 32;
  int tx = threadIdx.x & 31, ty = threadIdx.x >> 5;  // 32 x 8
#pragma unroll
  for (int i = 0; i < 32; i += 8) {
    int k = k0 + ty + i;
    float v = (k < Hdim) ? Wxh[(size_t)k * Ndim + n0 + tx]
                         : Whh[(size_t)(k - Hdim) * Ndim + n0 + tx];
    tile[ty + i][tx] = v;
  }
  __syncthreads();
#pragma unroll
  for (int i = 0; i < 32; i += 8) {
    int n = n0 + ty + i;
    Wt[(size_t)n * Kdim + k0 + tx] = f2bf(tile[tx][ty + i]);
  }
}

// ---------- GEMM: C[M][N] (bf16) = A[M][K] * Wt[N][K]^T ----------
// 256x256 tile, BK=64, 8 waves (2M x 4N), 16x16x32 MFMA.
// v9 = R8 with the post-QUAD barriers DELETED (one barrier per phase, 4/K-tile
// instead of 8). QUADs are register-only, so the post-QUAD barrier only forced
// wave lockstep; with it gone, a wave finishing its QUAD issues the next
// phase's ds_reads while slower waves still MFMA (cross-wave LDS/MFMA overlap).
// Happens-before that keeps WAR safety: wave v at barrier_k  =>  v executed
// phase k-1's lgkmcnt(0)  =>  v's phase k-2 reads drained. Region staleness:
// B0 4 phases, B1 3, A1 2 (P3 barrier between read@P2 and stage@P4) -> all
// pre-barrier OK; A0's last read is the IMMEDIATELY preceding phase (P2), so
// its stage moves to AFTER the P3 barrier.
#define BM 256
#define BN 256
#define BK 64
#define NT (Kdim / BK)   // 32

#define LGKM0_SB() do {                                              \
    asm volatile("s_waitcnt lgkmcnt(0)" ::: "memory");               \
    __builtin_amdgcn_sched_barrier(0);                               \
  } while (0)

__global__ __launch_bounds__(512, 2)
void gemm_kernel(const unsigned short* __restrict__ A, const unsigned short* __restrict__ Bt,
                 unsigned short* __restrict__ C) {
  __shared__ unsigned short lds[2][2][BM * BK];   // 128 KiB
  const int tid = threadIdx.x;
  int bid = blockIdx.x;
  int id = (bid & 7) * 64 + (bid >> 3);      // XCD swizzle (512 % 8 == 0, bijective)
  int mT = id >> 4, nT = id & 15;            // 32 x 16 tiles
  size_t m0 = (size_t)mT * BM, n0 = (size_t)nT * BN;
  const int lane = tid & 63, w = tid >> 6;
  const int wm = w >> 2, wn = w & 3;         // 2x4 waves -> 128x64 output each
  const int r16 = lane & 15, q = lane >> 4;

  const unsigned short* gA = A + m0 * Kdim;
  const unsigned short* gB = Bt + n0 * Kdim;

  // stage one half-tile (region: 0=A rows0-127, 1=A rows128-255, 2=B0, 3=B1).
  // LDS dest linear; slot swizzle stored_slot = logical_slot ^ (row&7) applied
  // on the GLOBAL source (rule #21).
  auto stage = [&](int b, int kt, int region) {
    const int mat = region >> 1, half = region & 1;
    const unsigned short* g = mat ? gB : gA;
#pragma unroll
    for (int it = 0; it < 2; ++it) {
      int c = it * 512 + tid;                // 1024 chunks of 16 B per half-tile
      int rr = c >> 3, ss = c & 7;
      __builtin_amdgcn_global_load_lds(
          (const __attribute__((address_space(1))) void*)(
              g + (size_t)(half * 128 + rr) * Kdim + kt * BK + ((ss ^ (rr & 7)) << 3)),
          (__attribute__((address_space(3))) void*)(&lds[b][mat][half * (128 * BK) + c * 8]),
          16, 0, 0);
    }
  };

  f32x4 acc[8][4] = {};
  bf16x8 av0[4][2], av1[4][2], bv0[2][2], bv1[2][2];

  auto readA = [&](int cur, int mh, bf16x8 (&av)[4][2]) {
#pragma unroll
    for (int mi = 0; mi < 4; ++mi) {
      int lr = wm * 128 + mh * 64 + mi * 16 + r16;
      const unsigned short* base = &lds[cur][0][lr * BK];
#pragma unroll
      for (int ks = 0; ks < 2; ++ks)
        av[mi][ks] = *(const bf16x8*)(base + ((((ks << 2) | q) ^ (lr & 7)) << 3));
    }
  };
  auto readB = [&](int cur, int nh, bf16x8 (&bv)[2][2]) {
#pragma unroll
    for (int ni = 0; ni < 2; ++ni) {
      int lr = wn * 64 + nh * 32 + ni * 16 + r16;
      const unsigned short* base = &lds[cur][1][lr * BK];
#pragma unroll
      for (int ks = 0; ks < 2; ++ks)
        bv[ni][ks] = *(const bf16x8*)(base + ((((ks << 2) | q) ^ (lr & 7)) << 3));
    }
  };

#define QUAD(AV, BV, MI0, NI0)                                                        \
  do {                                                                                \
    __builtin_amdgcn_s_setprio(1);                                                    \
    _Pragma("unroll") for (int mi = 0; mi < 4; ++mi)                                  \
      _Pragma("unroll") for (int ni = 0; ni < 2; ++ni)                                \
        _Pragma("unroll") for (int ks = 0; ks < 2; ++ks)                              \
          acc[(MI0) + mi][(NI0) + ni] = __builtin_amdgcn_mfma_f32_16x16x32_bf16(      \
              AV[mi][ks], BV[ni][ks], acc[(MI0) + mi][(NI0) + ni], 0, 0, 0);          \
    __builtin_amdgcn_s_setprio(0);                                                    \
  } while (0)

  // prologue: 6 half-tiles in flight; vmcnt(4) -> tile0 resident, A(t1) in
  // flight. Loop invariant entering iter t: tile t resident; in-flight =
  // {A0(t+1), A1(t+1)} (4 ops).
  stage(0, 0, 0); stage(0, 0, 1); stage(0, 0, 2); stage(0, 0, 3);
  stage(1, 1, 0); stage(1, 1, 1);
  asm volatile("s_waitcnt vmcnt(4)" ::: "memory");
  __builtin_amdgcn_s_barrier();

  // main loop: ONE barrier per phase.
#pragma unroll 1
  for (int t = 0; t < NT - 2; ++t) {
    int cur = t & 1, nxt = cur ^ 1;
    // P1: reads av0+bv0; stage B0(t+1) (B0(nxt) 4 phases stale)
    readA(cur, 0, av0);
    readB(cur, 0, bv0);
    stage(nxt, t + 1, 2);
    __builtin_amdgcn_s_barrier();
    LGKM0_SB();
    QUAD(av0, bv0, 0, 0);
    // P2: reads av1; stage B1(t+1) (B1(nxt) 3 phases stale)
    readA(cur, 1, av1);
    stage(nxt, t + 1, 3);
    __builtin_amdgcn_s_barrier();
    LGKM0_SB();
    QUAD(av1, bv0, 4, 0);
    // P3: reads bv1; stage A0(t+2) AFTER the barrier (A0(cur) last read @P2;
    // barrier => all waves did P2 lgkm0)
    readB(cur, 1, bv1);
    __builtin_amdgcn_s_barrier();
    LGKM0_SB();
    stage(cur, t + 2, 0);
    QUAD(av1, bv1, 4, 2);
    // P4: stage A1(t+2) (A1(cur) last read @P2, P3 barrier between);
    // vmcnt(4) retires tile t+1's 8 ops, leaves A0/A1(t+2)
    stage(cur, t + 2, 1);
    asm volatile("s_waitcnt vmcnt(4)" ::: "memory");
    __builtin_amdgcn_s_barrier();
    LGKM0_SB();
    QUAD(av0, bv1, 0, 2);
  }
  // t = NT-2: stage B(NT-1) at P1/P2; full drain at P4
  {
    const int cur = (NT - 2) & 1, nxt = cur ^ 1;
    readA(cur, 0, av0);
    readB(cur, 0, bv0);
    stage(nxt, NT - 1, 2);
    __builtin_amdgcn_s_barrier();
    LGKM0_SB();
    QUAD(av0, bv0, 0, 0);
    readA(cur, 1, av1);
    stage(nxt, NT - 1, 3);
    __builtin_amdgcn_s_barrier();
    LGKM0_SB();
    QUAD(av1, bv0, 4, 0);
    readB(cur, 1, bv1);
    __builtin_amdgcn_s_barrier();
    LGKM0_SB();
    QUAD(av1, bv1, 4, 2);
    asm volatile("s_waitcnt vmcnt(0)" ::: "memory");
    __builtin_amdgcn_s_barrier();
    LGKM0_SB();
    QUAD(av0, bv1, 0, 2);
  }
  // t = NT-1: all resident; one barrier to cover the NT-2 block's in-flight
  // reads is already done above; dependency-ordered reads + QUADs.
  {
    const int cur = (NT - 1) & 1;
    readA(cur, 0, av0);
    readB(cur, 0, bv0);
    QUAD(av0, bv0, 0, 0);
    readA(cur, 1, av1);
    QUAD(av1, bv0, 4, 0);
    readB(cur, 1, bv1);
    QUAD(av1, bv1, 4, 2);
    QUAD(av0, bv1, 0, 2);
  }
#undef QUAD

  // epilogue: D layout col = lane&15, row = (lane>>4)*4 + j
#pragma unroll
  for (int mi = 0; mi < 8; ++mi) {
#pragma unroll
    for (int ni = 0; ni < 4; ++ni) {
      size_t row = m0 + wm * 128 + mi * 16 + q * 4;
      size_t col = n0 + wn * 64 + ni * 16 + r16;
#pragma unroll
      for (int j = 0; j < 4; ++j)
        C[(row + j) * Ndim + col] = f2bf(acc[mi][ni][j]);
    }
  }
}

// ---------- tail: bias + group LN + gates + c LN + outputs ----------
__global__ __launch_bounds__(256)
void tail_kernel(const unsigned short* __restrict__ Cc, const float* __restrict__ cin,
                 const float* __restrict__ bias, const float* __restrict__ gamma,
                 const float* __restrict__ beta, const float* __restrict__ cg,
                 const float* __restrict__ cb, float* __restrict__ out) {
  int lane = threadIdx.x & 63;
  int wid = threadIdx.x >> 6;
  int row = blockIdx.x * 4 + wid;     // one wave per row
  const int base = lane * 16;         // 16 columns per lane

  const float4* cp = (const float4*)(cin + (size_t)row * Hdim + base);
  float4 c0 = cp[0], c1 = cp[1], c2 = cp[2], c3 = cp[3];
  float cv[16] = {c0.x, c0.y, c0.z, c0.w, c1.x, c1.y, c1.z, c1.w,
                  c2.x, c2.y, c2.z, c2.w, c3.x, c3.y, c3.z, c3.w};

  float accv[16];   // running sig(i)*tanh(j), then new_c
  float ov[16];     // sig(o)

#pragma unroll
  for (int g = 0; g < 4; ++g) {
    const int4* pp = (const int4*)(Cc + (size_t)row * Ndim + g * Hdim + base);
    int4 u0 = pp[0], u1 = pp[1];
    float vals[16];
    {
      int uu[8] = {u0.x, u0.y, u0.z, u0.w, u1.x, u1.y, u1.z, u1.w};
#pragma unroll
      for (int i = 0; i < 8; ++i) {
        vals[2 * i]     = bf2f((unsigned short)(uu[i] & 0xffff));
        vals[2 * i + 1] = bf2f((unsigned short)(((unsigned)uu[i]) >> 16));
      }
    }
    const float* bp = bias + g * Hdim + base;
#pragma unroll
    for (int t = 0; t < 16; ++t) vals[t] += bp[t];
    float s = 0.f, ss = 0.f;
#pragma unroll
    for (int t = 0; t < 16; ++t) { s += vals[t]; ss += vals[t] * vals[t]; }
#pragma unroll
    for (int off = 32; off; off >>= 1) { s += __shfl_xor(s, off); ss += __shfl_xor(ss, off); }
    float mean = s * (1.f / 1024.f);
    float rstd = rsqrtf(ss * (1.f / 1024.f) - mean * mean + 1e-3f);
    const float* gp = gamma + g * Hdim + base;
    const float* bb = beta + g * Hdim + base;
    if (g == 0) {
#pragma unroll
      for (int t = 0; t < 16; ++t)
        accv[t] = sigmoidf_((vals[t] - mean) * rstd * gp[t] + bb[t]);
    } else if (g == 1) {
#pragma unroll
      for (int t = 0; t < 16; ++t)
        accv[t] *= tanhf_((vals[t] - mean) * rstd * gp[t] + bb[t]);
    } else if (g == 2) {
#pragma unroll
      for (int t = 0; t < 16; ++t)
        accv[t] = cv[t] * sigmoidf_((vals[t] - mean) * rstd * gp[t] + bb[t] + 1.f) + accv[t];
    } else {
#pragma unroll
      for (int t = 0; t < 16; ++t)
        ov[t] = sigmoidf_((vals[t] - mean) * rstd * gp[t] + bb[t]);
    }
  }

  float s = 0.f, ss = 0.f;
#pragma unroll
  for (int t = 0; t < 16; ++t) { s += accv[t]; ss += accv[t] * accv[t]; }
#pragma unroll
  for (int off = 32; off; off >>= 1) { s += __shfl_xor(s, off); ss += __shfl_xor(ss, off); }
  float mean = s * (1.f / 1024.f);
  float rstd = rsqrtf(ss * (1.f / 1024.f) - mean * mean + 1e-3f);

  const float* cgp = cg + base;
  const float* cbp = cb + base;
  float hv[16];
#pragma unroll
  for (int t = 0; t < 16; ++t) {
    float cl = (accv[t] - mean) * rstd * cgp[t] + cbp[t];
    hv[t] = tanhf_(cl) * ov[t];
  }

  float4* oh = (float4*)(out + (size_t)row * Hdim + base);
  float4* oc = (float4*)(out + (size_t)Mdim * Hdim + (size_t)row * Hdim + base);
#pragma unroll
  for (int v = 0; v < 4; ++v) {
    oh[v] = make_float4(hv[4 * v], hv[4 * v + 1], hv[4 * v + 2], hv[4 * v + 3]);
    oc[v] = make_float4(accv[4 * v], accv[4 * v + 1], accv[4 * v + 2], accv[4 * v + 3]);
  }
}

extern "C" void kernel_launch(void* const* d_in, const int* in_sizes, int n_in,
                              void* d_out, int out_size, void* d_ws, size_t ws_size,
                              hipStream_t stream) {
  const float* x    = (const float*)d_in[0];
  const float* c    = (const float*)d_in[1];
  const float* h    = (const float*)d_in[2];
  const float* Wxh  = (const float*)d_in[3];
  const float* Whh  = (const float*)d_in[4];
  const float* bias = (const float*)d_in[5];
  const float* lng  = (const float*)d_in[6];
  const float* lnb  = (const float*)d_in[7];
  const float* cg   = (const float*)d_in[8];
  const float* cb   = (const float*)d_in[9];
  float* out = (float*)d_out;

  unsigned short* Abf = (unsigned short*)d_ws;                  // 32 MiB
  unsigned short* Wt  = Abf + (size_t)Mdim * Kdim;              // 16 MiB
  unsigned short* Cc  = Wt  + (size_t)Ndim * Kdim;              // 64 MiB

  pack_kernel<<<16384, 256, 0, stream>>>(x, h, Wxh, Whh, Abf, Wt);
  gemm_kernel<<<(Mdim / BM) * (Ndim / BN), 512, 0, stream>>>(Abf, Wt, Cc);
  tail_kernel<<<Mdim / 4, 256, 0, stream>>>(Cc, c, bias, lng, lnb, cg, cb, out);
}